// Round 4
// baseline (1449.263 us; speedup 1.0000x reference)
//
#include <hip/hip_runtime.h>
#include <cstdint>
#include <cstddef>

// ---------------------------------------------------------------------------
// GIN forward, bf16-MFMA, 256^2-tile 8-wave counted-vmcnt pipeline.
// enc MLP -> CSR gather-agg -> conv MLP(+res) -> dec MLP.
// GEMM: BM=BN=256, BK=64, 8 waves (2Mx4N), LDS 128 KiB double-buffered,
// T1 XCD swizzle + T2 LDS XOR swizzle + T3/T4 counted vmcnt + T5 setprio.
// ---------------------------------------------------------------------------

typedef __attribute__((ext_vector_type(8))) __bf16 bf16x8;
typedef __attribute__((ext_vector_type(4))) float f32x4;

__device__ __forceinline__ unsigned short f2bf(float f) {
    unsigned int u = __float_as_uint(f);
    u += 0x7FFF + ((u >> 16) & 1);          // RNE
    return (unsigned short)(u >> 16);
}
__device__ __forceinline__ float bf2f(unsigned int s) {
    return __uint_as_float(s << 16);
}

// ---------------------------- bf16 MFMA GEMM 256^2 --------------------------
// C[M,N] = epilogue(A[M,K] @ W[K,N]), W given transposed Wt[N,K], all bf16.
// Wave w: wr=w>>2 (128-row half), wc=w&3 (64-col quarter). acc: 8x4 f32x4.
template<bool RELU, bool HAS_RES, bool SF32>
__global__ __launch_bounds__(512, 2)
void gemm256(const unsigned short* __restrict__ A,
             const unsigned short* __restrict__ Wt,
             const float* __restrict__ Bias,
             const unsigned short* __restrict__ Res,
             float* __restrict__ Cf, unsigned short* __restrict__ Cb,
             int M, int K, int N, int MT)
{
    __shared__ unsigned short lds[65536];   // 128 KiB: A[2buf][2half][128][64] | B same

    // T1: bijective XCD-aware remap (m204)
    const int nwg = gridDim.x;
    const int qq = nwg >> 3, rr = nwg & 7;
    const int xc = blockIdx.x & 7, ii = blockIdx.x >> 3;
    const int wg = (xc < rr ? xc * (qq + 1) : rr * (qq + 1) + (xc - rr) * qq) + ii;
    const int ntile = wg / MT;
    const int mtile = wg - ntile * MT;
    const int m0 = mtile * 256;
    const int n0 = ntile * 256;

    const int tid  = threadIdx.x;
    const int wave = tid >> 6;
    const int lane = tid & 63;
    const int wr = wave >> 2;               // 0..1
    const int wc = wave & 3;                // 0..3

    f32x4 acc[8][4];
#pragma unroll
    for (int i = 0; i < 8; ++i)
#pragma unroll
        for (int j = 0; j < 4; ++j) acc[i][j] = (f32x4){0.f, 0.f, 0.f, 0.f};

    // staging geometry: slot = 16B; wave handles 64-slot (1 KiB) runs.
    // T2 swizzle (involution): LDS slot (row, c) holds global (row, c ^ (row&7)).
    const int rowoff = lane >> 3;                       // 0..7
    const int kcolbase = (((lane & 7) ^ rowoff) << 3);  // pre-swizzled source col

    auto stage = [&](int buf, int k0) {
#pragma unroll
        for (int h = 0; h < 2; ++h)
#pragma unroll
            for (int q = 0; q < 2; ++q) {
                const int rb = (q * 8 + wave) * 8 + rowoff;      // 0..127 in half
                int gm = m0 + h * 128 + rb;
                gm = (gm < M) ? gm : (M - 1);                    // M-tail clamp
                const unsigned short* gp = A + (size_t)gm * K + k0 + kcolbase;
                unsigned short* lp = &lds[buf * 16384 + h * 8192 + (q * 8 + wave) * 512];
                __builtin_amdgcn_global_load_lds(
                    (const __attribute__((address_space(1))) void*)gp,
                    (__attribute__((address_space(3))) void*)lp, 16, 0, 0);
            }
#pragma unroll
        for (int h = 0; h < 2; ++h)
#pragma unroll
            for (int q = 0; q < 2; ++q) {
                const int rb = (q * 8 + wave) * 8 + rowoff;
                const int gn = n0 + h * 128 + rb;    // N=128: over-read lands in ws (cols discarded)
                const unsigned short* gp = Wt + (size_t)gn * K + k0 + kcolbase;
                unsigned short* lp = &lds[32768 + buf * 16384 + h * 8192 + (q * 8 + wave) * 512];
                __builtin_amdgcn_global_load_lds(
                    (const __attribute__((address_space(1))) void*)gp,
                    (__attribute__((address_space(3))) void*)lp, 16, 0, 0);
            }
    };

    const int KT = K >> 6;
    stage(0, 0);                                     // prologue: tile 0 (8 loads)

    const int lr  = lane & 15;
    const int lkw = lane >> 4;                       // 0..3
    const int Abase = wr * 8192;
    const int Bbase = 32768 + ((wc >> 1) * 8192);
    const int brow0 = (wc & 1) * 64;

    int buf = 0;
    for (int t = 0; t < KT; ++t) {
        if (t + 1 < KT) {
            stage(buf ^ 1, (t + 1) << 6);            // prefetch next tile (8 loads)
            asm volatile("s_waitcnt vmcnt(8)" ::: "memory");   // tile t done; t+1 in flight
        } else {
            asm volatile("s_waitcnt vmcnt(0)" ::: "memory");
        }
        __builtin_amdgcn_s_barrier();
        asm volatile("" ::: "memory");

        const int ab = Abase + buf * 16384;
        const int bb = Bbase + buf * 16384;
#pragma unroll
        for (int ksi = 0; ksi < 2; ++ksi) {
            const int c16 = ksi * 4 + lkw;
            bf16x8 bg[4];
#pragma unroll
            for (int f = 0; f < 4; ++f) {
                const int rb = brow0 + f * 16 + lr;
                bg[f] = *(const bf16x8*)&lds[bb + rb * 64 + ((c16 ^ (rb & 7)) << 3)];
            }
#pragma unroll
            for (int mh = 0; mh < 2; ++mh) {
                bf16x8 af[4];
#pragma unroll
                for (int f = 0; f < 4; ++f) {
                    const int r = (mh * 4 + f) * 16 + lr;
                    af[f] = *(const bf16x8*)&lds[ab + r * 64 + ((c16 ^ (r & 7)) << 3)];
                }
                __builtin_amdgcn_s_setprio(1);
#pragma unroll
                for (int f = 0; f < 4; ++f)
#pragma unroll
                    for (int nf = 0; nf < 4; ++nf)
                        acc[mh * 4 + f][nf] = __builtin_amdgcn_mfma_f32_16x16x32_bf16(
                            af[f], bg[nf], acc[mh * 4 + f][nf], 0, 0, 0);
                __builtin_amdgcn_s_setprio(0);
            }
        }

        asm volatile("" ::: "memory");
        __builtin_amdgcn_s_barrier();
        buf ^= 1;
    }

    // epilogue: C/D layout col=lane&15, row=(lane>>4)*4+reg  [m89/m91]
    const int lg = lane >> 4;
#pragma unroll
    for (int mf = 0; mf < 8; ++mf) {
#pragma unroll
        for (int r = 0; r < 4; ++r) {
            const int row = m0 + wr * 128 + mf * 16 + lg * 4 + r;
            if (row >= M) continue;
#pragma unroll
            for (int nf = 0; nf < 4; ++nf) {
                const int col = n0 + wc * 64 + nf * 16 + lr;
                if (col >= N) continue;
                float v = acc[mf][nf][r] + Bias[col];
                if (RELU) v = fmaxf(v, 0.f);
                if (HAS_RES) v += bf2f(Res[(size_t)row * N + col]);
                if (SF32) Cf[(size_t)row * N + col] = v;
                else      Cb[(size_t)row * N + col] = f2bf(v);
            }
        }
    }
}

// ----------------------- weight convert + transpose (tiled) -----------------
__global__ __launch_bounds__(256)
void wt_kernel(const float* __restrict__ W, unsigned short* __restrict__ Wt,
               int K, int N)
{
    __shared__ unsigned short t[64][72];           // [n][k], stride 144B (16B-mult)
    const int kb = blockIdx.x * 64, nb = blockIdx.y * 64;
    const int tid = threadIdx.x;
    const int kl = tid >> 4, n4 = (tid & 15) << 2;
#pragma unroll
    for (int it = 0; it < 4; ++it) {
        const int k = kl + it * 16;
        const float4 v = *(const float4*)&W[(size_t)(kb + k) * N + nb + n4];
        t[n4 + 0][k] = f2bf(v.x); t[n4 + 1][k] = f2bf(v.y);
        t[n4 + 2][k] = f2bf(v.z); t[n4 + 3][k] = f2bf(v.w);
    }
    __syncthreads();
    const int n = tid >> 2, kc = (tid & 3) << 4;
    *(uint4*)&Wt[(size_t)(nb + n) * K + kb + kc]     = *(const uint4*)&t[n][kc];
    *(uint4*)&Wt[(size_t)(nb + n) * K + kb + kc + 8] = *(const uint4*)&t[n][kc + 8];
}

__global__ __launch_bounds__(256)
void cvt4_kernel(const float* __restrict__ in, unsigned short* __restrict__ out, int n4)
{
    const int i = blockIdx.x * 256 + threadIdx.x;
    if (i >= n4) return;
    const float4 v = ((const float4*)in)[i];
    ushort4 o;
    o.x = f2bf(v.x); o.y = f2bf(v.y); o.z = f2bf(v.z); o.w = f2bf(v.w);
    ((ushort4*)out)[i] = o;
}

// ------------------------- CSR build (counting sort) ------------------------
__global__ __launch_bounds__(256)
void zero_ints(int* __restrict__ p, int n)
{
    const int i = blockIdx.x * 256 + threadIdx.x;
    if (i < n) p[i] = 0;
}

__global__ __launch_bounds__(256)
void hist_kernel(const int* __restrict__ ei, int* __restrict__ cnt, int E)
{
    const int e = blockIdx.x * 256 + threadIdx.x;
    if (e < E) atomicAdd(&cnt[ei[E + e]], 1);
}

__global__ __launch_bounds__(256)
void scan_reduce(const int* __restrict__ cnt, int* __restrict__ bsum, int N)
{
    __shared__ int s[256];
    const int i = blockIdx.x * 256 + threadIdx.x;
    s[threadIdx.x] = (i < N) ? cnt[i] : 0;
    __syncthreads();
#pragma unroll
    for (int off = 128; off > 0; off >>= 1) {
        if (threadIdx.x < off) s[threadIdx.x] += s[threadIdx.x + off];
        __syncthreads();
    }
    if (threadIdx.x == 0) bsum[blockIdx.x] = s[0];
}

__global__ __launch_bounds__(512)
void scan_blocksums(int* __restrict__ bsum, int NB)
{
    __shared__ int a[512], b[512];
    const int t = threadIdx.x;
    const int v = (t < NB) ? bsum[t] : 0;
    a[t] = v;
    __syncthreads();
    int* s = a; int* d = b;
    for (int off = 1; off < 512; off <<= 1) {
        int x = s[t];
        if (t >= off) x += s[t - off];
        d[t] = x;
        __syncthreads();
        int* tmp = s; s = d; d = tmp;
    }
    if (t < NB) bsum[t] = s[t] - v;
}

__global__ __launch_bounds__(256)
void scan_final(const int* __restrict__ cnt, const int* __restrict__ bpre,
                int* __restrict__ off, int* __restrict__ cur, int N)
{
    __shared__ int a[256], b[256];
    const int i = blockIdx.x * 256 + threadIdx.x;
    const int t = threadIdx.x;
    const int v = (i < N) ? cnt[i] : 0;
    a[t] = v;
    __syncthreads();
    int* s = a; int* d = b;
    for (int o = 1; o < 256; o <<= 1) {
        int x = s[t];
        if (t >= o) x += s[t - o];
        d[t] = x;
        __syncthreads();
        int* tmp = s; s = d; d = tmp;
    }
    const int excl = s[t] - v + bpre[blockIdx.x];
    if (i < N) {
        off[i] = excl;
        cur[i] = excl;
        if (i == N - 1) off[N] = excl + v;
    }
}

__global__ __launch_bounds__(256)
void order_kernel(const int* __restrict__ ei, int* __restrict__ cur,
                  int* __restrict__ ssrc, int E)
{
    const int e = blockIdx.x * 256 + threadIdx.x;
    if (e >= E) return;
    const int s = ei[e];
    const int d = ei[E + e];
    const int pos = atomicAdd(&cur[d], 1);
    ssrc[pos] = s;
}

// one wave per node: hpg[i] = h[i] + sum h[src]; 4-way unrolled for load ILP
__global__ __launch_bounds__(256)
void agg_kernel(const unsigned short* __restrict__ hbf, const int* __restrict__ off,
                const int* __restrict__ ssrc, unsigned short* __restrict__ hpg, int Nn)
{
    const int wid  = (int)((blockIdx.x * 256 + threadIdx.x) >> 6);
    const int lane = threadIdx.x & 63;
    if (wid >= Nn) return;
    const int e0 = off[wid], e1 = off[wid + 1];
    const uint2* base = (const uint2*)hbf;

    uint2 u = base[(size_t)wid * 64 + lane];
    float a0 = bf2f(u.x & 0xffffu), a1 = bf2f(u.x >> 16);
    float a2 = bf2f(u.y & 0xffffu), a3 = bf2f(u.y >> 16);

    int e = e0;
    for (; e + 3 < e1; e += 4) {
        const uint2 v0 = base[(size_t)ssrc[e]     * 64 + lane];
        const uint2 v1 = base[(size_t)ssrc[e + 1] * 64 + lane];
        const uint2 v2 = base[(size_t)ssrc[e + 2] * 64 + lane];
        const uint2 v3 = base[(size_t)ssrc[e + 3] * 64 + lane];
        a0 += bf2f(v0.x & 0xffffu) + bf2f(v1.x & 0xffffu) + bf2f(v2.x & 0xffffu) + bf2f(v3.x & 0xffffu);
        a1 += bf2f(v0.x >> 16)     + bf2f(v1.x >> 16)     + bf2f(v2.x >> 16)     + bf2f(v3.x >> 16);
        a2 += bf2f(v0.y & 0xffffu) + bf2f(v1.y & 0xffffu) + bf2f(v2.y & 0xffffu) + bf2f(v3.y & 0xffffu);
        a3 += bf2f(v0.y >> 16)     + bf2f(v1.y >> 16)     + bf2f(v2.y >> 16)     + bf2f(v3.y >> 16);
    }
    for (; e < e1; ++e) {
        const uint2 v0 = base[(size_t)ssrc[e] * 64 + lane];
        a0 += bf2f(v0.x & 0xffffu); a1 += bf2f(v0.x >> 16);
        a2 += bf2f(v0.y & 0xffffu); a3 += bf2f(v0.y >> 16);
    }
    uint2 o;
    o.x = (unsigned)f2bf(a0) | ((unsigned)f2bf(a1) << 16);
    o.y = (unsigned)f2bf(a2) | ((unsigned)f2bf(a3) << 16);
    ((uint2*)hpg)[(size_t)wid * 64 + lane] = o;
}

// ---------------------------------------------------------------------------

extern "C" void kernel_launch(void* const* d_in, const int* in_sizes, int n_in,
                              void* d_out, int out_size, void* d_ws, size_t ws_size,
                              hipStream_t stream)
{
    const float* x  = (const float*)d_in[0];
    const int*   ei = (const int*)d_in[1];
    const float* W[9]  = {(const float*)d_in[3],  (const float*)d_in[5],  (const float*)d_in[7],
                          (const float*)d_in[9],  (const float*)d_in[11], (const float*)d_in[13],
                          (const float*)d_in[15], (const float*)d_in[17], (const float*)d_in[19]};
    const float* B[9]  = {(const float*)d_in[4],  (const float*)d_in[6],  (const float*)d_in[8],
                          (const float*)d_in[10], (const float*)d_in[12], (const float*)d_in[14],
                          (const float*)d_in[16], (const float*)d_in[18], (const float*)d_in[20]};
    const int    Kd[9] = {128, 512, 512, 256, 512, 512, 256, 512, 512};
    const int    Nd[9] = {512, 512, 256, 512, 512, 256, 512, 512, 128};
    float* out = (float*)d_out;

    const int M = 100000;
    const int E = 1600000;
    const size_t HN = (size_t)M * 256;

    char* p = (char*)d_ws;
    auto carve = [&](size_t bytes) -> char* {
        char* r = p;
        p += (bytes + 255) & ~(size_t)255;
        return r;
    };
    unsigned short* hbf   = (unsigned short*)carve(HN * 2);
    unsigned short* hpgbf = (unsigned short*)carve(HN * 2);
    unsigned short* xbf   = (unsigned short*)carve((size_t)M * 128 * 2);
    unsigned short* Wt[9];
    for (int i = 0; i < 9; ++i) Wt[i] = (unsigned short*)carve((size_t)Kd[i] * Nd[i] * 2);
    int* cnt  = (int*)carve(M * 4);
    int* off  = (int*)carve((M + 4) * 4);
    int* cur  = (int*)carve(M * 4);
    int* bsum = (int*)carve(512 * 4);
    int* ssrc = (int*)carve((size_t)E * 4);

    const size_t fixed = (size_t)(p - (char*)d_ws);
    size_t remain = (ws_size > fixed) ? ws_size - fixed : 0;
    long long ch = (long long)(remain / (2 * 512 * 2 + 64));
    if (ch > M) ch = M;
    ch &= ~255LL;
    if (ch < 256) ch = 256;
    const int CH = (int)ch;
    unsigned short* t1 = (unsigned short*)carve((size_t)CH * 512 * 2);
    unsigned short* t2 = (unsigned short*)carve((size_t)CH * 512 * 2);

    const dim3 blk(256);
    const dim3 gblk(512);
    const int NB = (M + 255) / 256;

    // ---- weight transpose+convert (tiled), x convert, CSR build ----
    for (int i = 0; i < 9; ++i)
        wt_kernel<<<dim3(Kd[i] / 64, Nd[i] / 64), blk, 0, stream>>>(W[i], Wt[i], Kd[i], Nd[i]);
    cvt4_kernel<<<(M * 128 / 4 + 255) / 256, blk, 0, stream>>>(x, xbf, M * 128 / 4);
    zero_ints<<<(M + 255) / 256, blk, 0, stream>>>(cnt, M);
    hist_kernel<<<(E + 255) / 256, blk, 0, stream>>>(ei, cnt, E);
    scan_reduce<<<NB, blk, 0, stream>>>(cnt, bsum, M);
    scan_blocksums<<<1, 512, 0, stream>>>(bsum, NB);
    scan_final<<<NB, blk, 0, stream>>>(cnt, bsum, off, cur, M);
    order_kernel<<<(E + 255) / 256, blk, 0, stream>>>(ei, cur, ssrc, E);

    auto mt = [](int m) { return (m + 255) / 256; };

    // ---- encoder: xbf ->(relu) t1 ->(relu) t2 ->(relu) hbf ----
    for (int m0 = 0; m0 < M; m0 += CH) {
        const int cm = (M - m0 < CH) ? (M - m0) : CH;
        const int MT = mt(cm);
        gemm256<true, false, false><<<dim3(MT * 2), gblk, 0, stream>>>(
            xbf + (size_t)m0 * 128, Wt[0], B[0], nullptr, nullptr, t1, cm, 128, 512, MT);
        gemm256<true, false, false><<<dim3(MT * 2), gblk, 0, stream>>>(
            t1, Wt[1], B[1], nullptr, nullptr, t2, cm, 512, 512, MT);
        gemm256<true, false, false><<<dim3(MT), gblk, 0, stream>>>(
            t2, Wt[2], B[2], nullptr, nullptr, hbf + (size_t)m0 * 256, cm, 512, 256, MT);
    }

    // ---- aggregation: hpg = h + sum_{src->i} h[src] ----
    agg_kernel<<<((size_t)M * 64 + 255) / 256, blk, 0, stream>>>(hbf, off, ssrc, hpgbf, M);

    // ---- conv MLP (+ residual h) ----
    for (int m0 = 0; m0 < M; m0 += CH) {
        const int cm = (M - m0 < CH) ? (M - m0) : CH;
        const int MT = mt(cm);
        gemm256<true, false, false><<<dim3(MT * 2), gblk, 0, stream>>>(
            hpgbf + (size_t)m0 * 256, Wt[3], B[3], nullptr, nullptr, t1, cm, 256, 512, MT);
        gemm256<true, false, false><<<dim3(MT * 2), gblk, 0, stream>>>(
            t1, Wt[4], B[4], nullptr, nullptr, t2, cm, 512, 512, MT);
        gemm256<true, true, false><<<dim3(MT), gblk, 0, stream>>>(
            t2, Wt[5], B[5], hbf + (size_t)m0 * 256, nullptr, hpgbf + (size_t)m0 * 256, cm, 512, 256, MT);
    }

    // ---- decoder: hpg ->(relu) t1 ->(relu) t2 -> out (f32, no act) ----
    for (int m0 = 0; m0 < M; m0 += CH) {
        const int cm = (M - m0 < CH) ? (M - m0) : CH;
        const int MT = mt(cm);
        gemm256<true, false, false><<<dim3(MT * 2), gblk, 0, stream>>>(
            hpgbf + (size_t)m0 * 256, Wt[6], B[6], nullptr, nullptr, t1, cm, 256, 512, MT);
        gemm256<true, false, false><<<dim3(MT * 2), gblk, 0, stream>>>(
            t1, Wt[7], B[7], nullptr, nullptr, t2, cm, 512, 512, MT);
        gemm256<false, false, true><<<dim3(MT), gblk, 0, stream>>>(
            t2, Wt[8], B[8], nullptr, out + (size_t)m0 * 128, nullptr, cm, 512, 128, MT);
    }
}

// Round 5
// 1083.030 us; speedup vs baseline: 1.3382x; 1.3382x over previous
//
#include <hip/hip_runtime.h>
#include <cstdint>
#include <cstddef>

// ---------------------------------------------------------------------------
// GIN forward, bf16-MFMA, 256x128-tile 4-phase counted-vmcnt pipeline (T2-T5).
// enc MLP -> CSR gather-agg -> conv MLP(+res) -> dec MLP.
// GEMM: BM=256, BN=128, BK=64, 8 waves (4Mx2N), LDS 96 KiB double-buffered,
// per-phase {ds_read || stage half-tile -> barrier -> 8 MFMA -> barrier},
// vmcnt(6) once per K-tile (3 half-tiles in flight), XOR-swizzled LDS.
// ---------------------------------------------------------------------------

typedef __attribute__((ext_vector_type(8))) __bf16 bf16x8;
typedef __attribute__((ext_vector_type(4))) float f32x4;

__device__ __forceinline__ unsigned short f2bf(float f) {
    unsigned int u = __float_as_uint(f);
    u += 0x7FFF + ((u >> 16) & 1);          // RNE
    return (unsigned short)(u >> 16);
}
__device__ __forceinline__ float bf2f(unsigned int s) {
    return __uint_as_float(s << 16);
}

#define FENCE asm volatile("" ::: "memory")
#define BAR   do { FENCE; __builtin_amdgcn_s_barrier(); FENCE; } while (0)

// ---------------------------- bf16 MFMA GEMM --------------------------------
// C[M,N] = epilogue(A[M,K] @ W[K,N]), W given transposed Wt[N,K], all bf16.
// 8 waves: wr=wave>>1 (64-row block), wc=wave&1 (64-col block). acc 4x4 f32x4.
template<bool RELU, bool HAS_RES, bool SF32>
__global__ __launch_bounds__(512, 2)
void gemm4p(const unsigned short* __restrict__ A,
            const unsigned short* __restrict__ Wt,
            const float* __restrict__ Bias,
            const unsigned short* __restrict__ Res,
            float* __restrict__ Cf, unsigned short* __restrict__ Cb,
            int M, int K, int N, int MT)
{
    // A: 2 bufs x [256][64] at 0 / 16384 (elem), B: 2 bufs x [128][64] at 32768 / 40960
    __shared__ unsigned short lds[49152];   // 96 KiB

    // T1: bijective XCD-aware remap (m204)
    const int nwg = gridDim.x;
    const int qq = nwg >> 3, rr = nwg & 7;
    const int xc = blockIdx.x & 7, ii = blockIdx.x >> 3;
    const int wg = (xc < rr ? xc * (qq + 1) : rr * (qq + 1) + (xc - rr) * qq) + ii;
    const int ntile = wg / MT;
    const int mtile = wg - ntile * MT;
    const int m0 = mtile * 256;
    const int n0 = ntile * 128;

    const int tid  = threadIdx.x;
    const int wave = tid >> 6;
    const int lane = tid & 63;
    const int wr = wave >> 1;               // 0..3
    const int wc = wave & 1;                // 0..1

    f32x4 acc[4][4];
#pragma unroll
    for (int i = 0; i < 4; ++i)
#pragma unroll
        for (int j = 0; j < 4; ++j) acc[i][j] = (f32x4){0.f, 0.f, 0.f, 0.f};

    // T2 swizzle (involution): LDS slot (row, c) holds global (row, c ^ (row&7)).
    const int rowoff = lane >> 3;                       // 0..7
    const int scol = (((lane & 7) ^ rowoff) << 3);      // pre-swizzled source col

    auto stageA = [&](int buf, int k0, int h) {         // half-tile: rows h*128..+127
#pragma unroll
        for (int j = 0; j < 2; ++j) {
            const int r = h * 128 + j * 64 + wave * 8 + rowoff;
            int gm = m0 + r; gm = (gm < M) ? gm : (M - 1);   // M-tail clamp
            const unsigned short* gp = A + (size_t)gm * K + k0 + scol;
            unsigned short* lp = &lds[buf * 16384 + (h * 128 + j * 64 + wave * 8) * 64];
            __builtin_amdgcn_global_load_lds(
                (const __attribute__((address_space(1))) void*)gp,
                (__attribute__((address_space(3))) void*)lp, 16, 0, 0);
        }
    };
    auto stageB = [&](int buf, int k0) {
#pragma unroll
        for (int j = 0; j < 2; ++j) {
            const int r = j * 64 + wave * 8 + rowoff;
            const unsigned short* gp = Wt + (size_t)(n0 + r) * K + k0 + scol;
            unsigned short* lp = &lds[32768 + buf * 8192 + (j * 64 + wave * 8) * 64];
            __builtin_amdgcn_global_load_lds(
                (const __attribute__((address_space(1))) void*)gp,
                (__attribute__((address_space(3))) void*)lp, 16, 0, 0);
        }
    };

    const int KT = K >> 6;
    // prologue: tiles 0,1 (6 half-tiles, 12 loads); wait tile 0 (leave 6 in flight)
    stageA(0, 0, 0);  stageA(0, 0, 1);  stageB(0, 0);
    stageA(1, 64, 0); stageA(1, 64, 1); stageB(1, 64);
    asm volatile("s_waitcnt vmcnt(6)" ::: "memory");
    BAR;

    const int lr  = lane & 15;
    const int lkw = lane >> 4;

    bf16x8 av[2][2], bv[2][2], bw[2][2];

    auto rdA = [&](bf16x8 (&d)[2][2], int ab, int mq) {
#pragma unroll
        for (int f = 0; f < 2; ++f)
#pragma unroll
            for (int ks = 0; ks < 2; ++ks) {
                const int ra = wr * 64 + (mq * 2 + f) * 16 + lr;
                const int c16 = ks * 4 + lkw;
                d[f][ks] = *(const bf16x8*)&lds[ab + ra * 64 + ((c16 ^ (ra & 7)) << 3)];
            }
    };
    auto rdB = [&](bf16x8 (&d)[2][2], int bb, int nq) {
#pragma unroll
        for (int f = 0; f < 2; ++f)
#pragma unroll
            for (int ks = 0; ks < 2; ++ks) {
                const int rb = wc * 64 + (nq * 2 + f) * 16 + lr;
                const int c16 = ks * 4 + lkw;
                d[f][ks] = *(const bf16x8*)&lds[bb + rb * 64 + ((c16 ^ (rb & 7)) << 3)];
            }
    };
    auto mma8 = [&](bf16x8 (&a)[2][2], bf16x8 (&b)[2][2], int mq, int nq) {
        __builtin_amdgcn_s_setprio(1);
#pragma unroll
        for (int f = 0; f < 2; ++f)
#pragma unroll
            for (int nf = 0; nf < 2; ++nf)
#pragma unroll
                for (int ks = 0; ks < 2; ++ks)
                    acc[mq * 2 + f][nq * 2 + nf] = __builtin_amdgcn_mfma_f32_16x16x32_bf16(
                        a[f][ks], b[nf][ks], acc[mq * 2 + f][nq * 2 + nf], 0, 0, 0);
        __builtin_amdgcn_s_setprio(0);
    };

    for (int t = 0; t < KT; ++t) {
        const int buf = t & 1;
        const int ab = buf * 16384;
        const int bb = 32768 + buf * 8192;
        const bool pf = (t + 2 < KT);
        const int k2 = (t + 2) << 6;

        // phase 1: quadrant (m-lo, n-lo)
        rdA(av, ab, 0); rdB(bv, bb, 0);
        BAR;
        mma8(av, bv, 0, 0);
        BAR;
        // phase 2: (m-lo, n-hi); prefetch A-half0 of tile t+2
        rdB(bw, bb, 1);
        if (pf) stageA(buf, k2, 0);
        BAR;
        mma8(av, bw, 0, 1);
        BAR;
        // phase 3: (m-hi, n-hi); prefetch A-half1
        rdA(av, ab, 1);
        if (pf) stageA(buf, k2, 1);
        BAR;
        mma8(av, bw, 1, 1);
        BAR;
        // phase 4: (m-hi, n-lo); prefetch B; counted wait (tile t+1 landed)
        rdB(bv, bb, 0);
        if (pf) stageB(buf, k2);
        BAR;
        mma8(av, bv, 1, 0);
        if (pf) asm volatile("s_waitcnt vmcnt(6)" ::: "memory");
        else    asm volatile("s_waitcnt vmcnt(0)" ::: "memory");
        BAR;
    }

    // epilogue: C/D layout col=lane&15, row=(lane>>4)*4+reg  [m89/m91]
    const int lg = lane >> 4;
#pragma unroll
    for (int mf = 0; mf < 4; ++mf) {
#pragma unroll
        for (int r = 0; r < 4; ++r) {
            const int row = m0 + wr * 64 + mf * 16 + lg * 4 + r;
            if (row >= M) continue;
#pragma unroll
            for (int nf = 0; nf < 4; ++nf) {
                const int col = n0 + wc * 64 + nf * 16 + lr;
                float v = acc[mf][nf][r] + Bias[col];
                if (RELU) v = fmaxf(v, 0.f);
                if (HAS_RES) v += bf2f(Res[(size_t)row * N + col]);
                if (SF32) Cf[(size_t)row * N + col] = v;
                else      Cb[(size_t)row * N + col] = f2bf(v);
            }
        }
    }
}

// ----------------- fused prep: 9x weight transpose + x cvt + cnt zero -------
struct PrepArgs {
    const float* W[9];
    unsigned short* Wt[9];
    int wstart[10];
    int Kd[9], Nd[9];
    const float* x;
    unsigned short* xbf;
    int* cnt;
    int wtTotal, cvtBlocks, nCvt4, nCnt;
};

__global__ __launch_bounds__(256)
void prep_kernel(PrepArgs a)
{
    __shared__ unsigned short t[64][72];
    const int b = blockIdx.x;
    const int tid = threadIdx.x;
    if (b < a.wtTotal) {
        int job = 0;
        while (b >= a.wstart[job + 1]) ++job;
        const int lb = b - a.wstart[job];
        const int K = a.Kd[job], N = a.Nd[job];
        const int kt = K >> 6;
        const int kb = (lb % kt) * 64, nb = (lb / kt) * 64;
        const float* W = a.W[job];
        unsigned short* Wt = a.Wt[job];
        const int kl = tid >> 4, n4 = (tid & 15) << 2;
#pragma unroll
        for (int it = 0; it < 4; ++it) {
            const int k = kl + it * 16;
            const float4 v = *(const float4*)&W[(size_t)(kb + k) * N + nb + n4];
            t[n4 + 0][k] = f2bf(v.x); t[n4 + 1][k] = f2bf(v.y);
            t[n4 + 2][k] = f2bf(v.z); t[n4 + 3][k] = f2bf(v.w);
        }
        __syncthreads();
        const int n = tid >> 2, kc = (tid & 3) << 4;
        *(uint4*)&Wt[(size_t)(nb + n) * K + kb + kc]     = *(const uint4*)&t[n][kc];
        *(uint4*)&Wt[(size_t)(nb + n) * K + kb + kc + 8] = *(const uint4*)&t[n][kc + 8];
    } else if (b < a.wtTotal + a.cvtBlocks) {
        const int i = (b - a.wtTotal) * 256 + tid;
        if (i < a.nCvt4) {
            const float4 v = ((const float4*)a.x)[i];
            ushort4 o;
            o.x = f2bf(v.x); o.y = f2bf(v.y); o.z = f2bf(v.z); o.w = f2bf(v.w);
            ((ushort4*)a.xbf)[i] = o;
        }
    } else {
        const int i = (b - a.wtTotal - a.cvtBlocks) * 256 + tid;
        if (i < a.nCnt) a.cnt[i] = 0;
    }
}

// ------------------------- CSR build (counting sort) ------------------------
__global__ __launch_bounds__(256)
void hist_kernel(const int* __restrict__ ei, int* __restrict__ cnt, int E)
{
    const int e = blockIdx.x * 256 + threadIdx.x;
    if (e < E) atomicAdd(&cnt[ei[E + e]], 1);
}

__global__ __launch_bounds__(256)
void scan_reduce(const int* __restrict__ cnt, int* __restrict__ bsum, int N)
{
    __shared__ int s[256];
    const int i = blockIdx.x * 256 + threadIdx.x;
    s[threadIdx.x] = (i < N) ? cnt[i] : 0;
    __syncthreads();
#pragma unroll
    for (int off = 128; off > 0; off >>= 1) {
        if (threadIdx.x < off) s[threadIdx.x] += s[threadIdx.x + off];
        __syncthreads();
    }
    if (threadIdx.x == 0) bsum[blockIdx.x] = s[0];
}

__global__ __launch_bounds__(512)
void scan_blocksums(int* __restrict__ bsum, int NB)
{
    __shared__ int a[512], b[512];
    const int t = threadIdx.x;
    const int v = (t < NB) ? bsum[t] : 0;
    a[t] = v;
    __syncthreads();
    int* s = a; int* d = b;
    for (int off = 1; off < 512; off <<= 1) {
        int x = s[t];
        if (t >= off) x += s[t - off];
        d[t] = x;
        __syncthreads();
        int* tmp = s; s = d; d = tmp;
    }
    if (t < NB) bsum[t] = s[t] - v;
}

__global__ __launch_bounds__(256)
void scan_final(const int* __restrict__ cnt, const int* __restrict__ bpre,
                int* __restrict__ off, int* __restrict__ cur, int N)
{
    __shared__ int a[256], b[256];
    const int i = blockIdx.x * 256 + threadIdx.x;
    const int t = threadIdx.x;
    const int v = (i < N) ? cnt[i] : 0;
    a[t] = v;
    __syncthreads();
    int* s = a; int* d = b;
    for (int o = 1; o < 256; o <<= 1) {
        int x = s[t];
        if (t >= o) x += s[t - o];
        d[t] = x;
        __syncthreads();
        int* tmp = s; s = d; d = tmp;
    }
    const int excl = s[t] - v + bpre[blockIdx.x];
    if (i < N) {
        off[i] = excl;
        cur[i] = excl;
        if (i == N - 1) off[N] = excl + v;
    }
}

__global__ __launch_bounds__(256)
void order_kernel(const int* __restrict__ ei, int* __restrict__ cur,
                  int* __restrict__ ssrc, int E)
{
    const int e = blockIdx.x * 256 + threadIdx.x;
    if (e >= E) return;
    const int s = ei[e];
    const int d = ei[E + e];
    const int pos = atomicAdd(&cur[d], 1);
    ssrc[pos] = s;
}

// 2 waves per node (128 ch each): hpg[i] = h[i] + sum h[src]
__global__ __launch_bounds__(256)
void agg_kernel(const unsigned short* __restrict__ hbf, const int* __restrict__ off,
                const int* __restrict__ ssrc, unsigned short* __restrict__ hpg, int Nn)
{
    const int gw   = (int)((blockIdx.x * 256 + threadIdx.x) >> 6);
    const int lane = threadIdx.x & 63;
    const int node = gw >> 1;
    if (node >= Nn) return;
    const int ci = (gw & 1) * 64 + lane;            // uint column 0..127
    const int e0 = off[node], e1 = off[node + 1];
    const unsigned int* base = (const unsigned int*)hbf;

    unsigned int u = base[(size_t)node * 128 + ci];
    float a0 = bf2f(u & 0xffffu), a1 = bf2f(u >> 16);

    int e = e0;
    for (; e + 3 < e1; e += 4) {
        const unsigned int v0 = base[(size_t)ssrc[e]     * 128 + ci];
        const unsigned int v1 = base[(size_t)ssrc[e + 1] * 128 + ci];
        const unsigned int v2 = base[(size_t)ssrc[e + 2] * 128 + ci];
        const unsigned int v3 = base[(size_t)ssrc[e + 3] * 128 + ci];
        a0 += bf2f(v0 & 0xffffu) + bf2f(v1 & 0xffffu) + bf2f(v2 & 0xffffu) + bf2f(v3 & 0xffffu);
        a1 += bf2f(v0 >> 16)     + bf2f(v1 >> 16)     + bf2f(v2 >> 16)     + bf2f(v3 >> 16);
    }
    for (; e < e1; ++e) {
        const unsigned int v0 = base[(size_t)ssrc[e] * 128 + ci];
        a0 += bf2f(v0 & 0xffffu); a1 += bf2f(v0 >> 16);
    }
    ((unsigned int*)hpg)[(size_t)node * 128 + ci] =
        (unsigned)f2bf(a0) | ((unsigned)f2bf(a1) << 16);
}

// ---------------------------------------------------------------------------

extern "C" void kernel_launch(void* const* d_in, const int* in_sizes, int n_in,
                              void* d_out, int out_size, void* d_ws, size_t ws_size,
                              hipStream_t stream)
{
    const float* x  = (const float*)d_in[0];
    const int*   ei = (const int*)d_in[1];
    const float* W[9]  = {(const float*)d_in[3],  (const float*)d_in[5],  (const float*)d_in[7],
                          (const float*)d_in[9],  (const float*)d_in[11], (const float*)d_in[13],
                          (const float*)d_in[15], (const float*)d_in[17], (const float*)d_in[19]};
    const float* B[9]  = {(const float*)d_in[4],  (const float*)d_in[6],  (const float*)d_in[8],
                          (const float*)d_in[10], (const float*)d_in[12], (const float*)d_in[14],
                          (const float*)d_in[16], (const float*)d_in[18], (const float*)d_in[20]};
    const int    Kd[9] = {128, 512, 512, 256, 512, 512, 256, 512, 512};
    const int    Nd[9] = {512, 512, 256, 512, 512, 256, 512, 512, 128};
    float* out = (float*)d_out;

    const int M = 100000;
    const int E = 1600000;
    const size_t HN = (size_t)M * 256;

    char* p = (char*)d_ws;
    auto carve = [&](size_t bytes) -> char* {
        char* r = p;
        p += (bytes + 255) & ~(size_t)255;
        return r;
    };
    unsigned short* hbf   = (unsigned short*)carve(HN * 2);
    unsigned short* hpgbf = (unsigned short*)carve(HN * 2);
    unsigned short* xbf   = (unsigned short*)carve((size_t)M * 128 * 2);
    unsigned short* Wt[9];
    for (int i = 0; i < 9; ++i) Wt[i] = (unsigned short*)carve((size_t)Kd[i] * Nd[i] * 2);
    int* cnt  = (int*)carve(M * 4);
    int* off  = (int*)carve((M + 4) * 4);
    int* cur  = (int*)carve(M * 4);
    int* bsum = (int*)carve(512 * 4);
    int* ssrc = (int*)carve((size_t)E * 4);

    const size_t fixed = (size_t)(p - (char*)d_ws);
    size_t remain = (ws_size > fixed) ? ws_size - fixed : 0;
    long long ch = (long long)(remain / (2 * 512 * 2 + 64));
    if (ch > M) ch = M;
    ch &= ~255LL;
    if (ch < 256) ch = 256;
    const int CH = (int)ch;
    unsigned short* t1 = (unsigned short*)carve((size_t)CH * 512 * 2);
    unsigned short* t2 = (unsigned short*)carve((size_t)CH * 512 * 2);

    const dim3 blk(256);
    const dim3 gblk(512);
    const int NB = (M + 255) / 256;

    // ---- fused prep: weight transposes + x convert + cnt zero ----
    PrepArgs pa;
    pa.wstart[0] = 0;
    for (int i = 0; i < 9; ++i) {
        pa.W[i] = W[i]; pa.Wt[i] = Wt[i]; pa.Kd[i] = Kd[i]; pa.Nd[i] = Nd[i];
        pa.wstart[i + 1] = pa.wstart[i] + (Kd[i] / 64) * (Nd[i] / 64);
    }
    pa.x = x; pa.xbf = xbf; pa.cnt = cnt;
    pa.wtTotal = pa.wstart[9];
    pa.nCvt4 = M * 128 / 4;
    pa.cvtBlocks = (pa.nCvt4 + 255) / 256;
    pa.nCnt = M;
    const int prepBlocks = pa.wtTotal + pa.cvtBlocks + NB;
    prep_kernel<<<prepBlocks, blk, 0, stream>>>(pa);

    // ---- CSR build ----
    hist_kernel<<<(E + 255) / 256, blk, 0, stream>>>(ei, cnt, E);
    scan_reduce<<<NB, blk, 0, stream>>>(cnt, bsum, M);
    scan_blocksums<<<1, 512, 0, stream>>>(bsum, NB);
    scan_final<<<NB, blk, 0, stream>>>(cnt, bsum, off, cur, M);
    order_kernel<<<(E + 255) / 256, blk, 0, stream>>>(ei, cur, ssrc, E);

    auto mt = [](int m) { return (m + 255) / 256; };

    // ---- encoder: xbf ->(relu) t1 ->(relu) t2 ->(relu) hbf ----
    for (int m0 = 0; m0 < M; m0 += CH) {
        const int cm = (M - m0 < CH) ? (M - m0) : CH;
        const int MT = mt(cm);
        gemm4p<true, false, false><<<dim3(MT * 4), gblk, 0, stream>>>(
            xbf + (size_t)m0 * 128, Wt[0], B[0], nullptr, nullptr, t1, cm, 128, 512, MT);
        gemm4p<true, false, false><<<dim3(MT * 4), gblk, 0, stream>>>(
            t1, Wt[1], B[1], nullptr, nullptr, t2, cm, 512, 512, MT);
        gemm4p<true, false, false><<<dim3(MT * 2), gblk, 0, stream>>>(
            t2, Wt[2], B[2], nullptr, nullptr, hbf + (size_t)m0 * 256, cm, 512, 256, MT);
    }

    // ---- aggregation: hpg = h + sum_{src->i} h[src] ----
    agg_kernel<<<(int)(((size_t)2 * M * 64 + 255) / 256), blk, 0, stream>>>(
        hbf, off, ssrc, hpgbf, M);

    // ---- conv MLP (+ residual h) ----
    for (int m0 = 0; m0 < M; m0 += CH) {
        const int cm = (M - m0 < CH) ? (M - m0) : CH;
        const int MT = mt(cm);
        gemm4p<true, false, false><<<dim3(MT * 4), gblk, 0, stream>>>(
            hpgbf + (size_t)m0 * 256, Wt[3], B[3], nullptr, nullptr, t1, cm, 256, 512, MT);
        gemm4p<true, false, false><<<dim3(MT * 4), gblk, 0, stream>>>(
            t1, Wt[4], B[4], nullptr, nullptr, t2, cm, 512, 512, MT);
        gemm4p<true, true, false><<<dim3(MT * 2), gblk, 0, stream>>>(
            t2, Wt[5], B[5], hbf + (size_t)m0 * 256, nullptr, hpgbf + (size_t)m0 * 256,
            cm, 512, 256, MT);
    }

    // ---- decoder: hpg ->(relu) t1 ->(relu) t2 -> out (f32, no act) ----
    for (int m0 = 0; m0 < M; m0 += CH) {
        const int cm = (M - m0 < CH) ? (M - m0) : CH;
        const int MT = mt(cm);
        gemm4p<true, false, false><<<dim3(MT * 4), gblk, 0, stream>>>(
            hpgbf + (size_t)m0 * 256, Wt[6], B[6], nullptr, nullptr, t1, cm, 256, 512, MT);
        gemm4p<true, false, false><<<dim3(MT * 4), gblk, 0, stream>>>(
            t1, Wt[7], B[7], nullptr, nullptr, t2, cm, 512, 512, MT);
        gemm4p<false, false, true><<<dim3(MT), gblk, 0, stream>>>(
            t2, Wt[8], B[8], nullptr, out + (size_t)m0 * 128, nullptr, cm, 512, 128, MT);
    }
}

// Round 6
// 1050.987 us; speedup vs baseline: 1.3790x; 1.0305x over previous
//
#include <hip/hip_runtime.h>
#include <cstdint>
#include <cstddef>

// ---------------------------------------------------------------------------
// GIN forward, bf16-MFMA (m97 128^2 structure, measured-best at these shapes).
// enc MLP -> CSR gather-agg -> conv MLP(+res) -> dec MLP.
// Round 6: revert GEMM to round-3 kernel; fuse order_kernel into enc1 launch
// (backfill blocks); balanced M-chunking (no runt chunks).
// ---------------------------------------------------------------------------

typedef __attribute__((ext_vector_type(8))) __bf16 bf16x8;
typedef __attribute__((ext_vector_type(4))) float f32x4;

__device__ __forceinline__ unsigned short f2bf(float f) {
    unsigned int u = __float_as_uint(f);
    u += 0x7FFF + ((u >> 16) & 1);          // RNE
    return (unsigned short)(u >> 16);
}
__device__ __forceinline__ float bf2f(unsigned int s) {
    return __uint_as_float(s << 16);
}

// ---------------------------- bf16 MFMA GEMM --------------------------------
// C[M,N] = epilogue(A[M,K](bf16) @ W[K,N]) with W transposed: Wt[N,K].
// 128x128 tile, 4 waves, BK=64, global_load_lds 16B staging (m97 structure).
// ORDER: trailing blocks (>= gemmBlocks) run the CSR bucket-scatter instead.
template<bool RELU, bool HAS_RES, bool SF32, bool ORDER>
__global__ __launch_bounds__(256, 2)
void gemm128(const unsigned short* __restrict__ A,
             const unsigned short* __restrict__ Wt,
             const float* __restrict__ Bias,
             const unsigned short* __restrict__ Res,
             float* __restrict__ Cf, unsigned short* __restrict__ Cb,
             int M, int K, int N, int MT, int gemmBlocks,
             const int* __restrict__ ei, int* __restrict__ cur,
             int* __restrict__ ssrc, int E)
{
    __shared__ unsigned short As[128 * 64];   // [row 0..127][k 0..63]
    __shared__ unsigned short Bs[128 * 64];   // [n   0..127][k 0..63]

    const int tid  = threadIdx.x;

    if (ORDER && (int)blockIdx.x >= gemmBlocks) {
        // CSR bucket scatter: pos = cur[dst]++; ssrc[pos] = src.
        const int nth = (gridDim.x - gemmBlocks) * 256;
        for (int e = (blockIdx.x - gemmBlocks) * 256 + tid; e < E; e += nth) {
            const int s = ei[e];
            const int d = ei[E + e];
            const int pos = atomicAdd(&cur[d], 1);
            ssrc[pos] = s;
        }
        return;
    }

    const int mtile = (int)blockIdx.x % MT;
    const int ntile = (int)blockIdx.x / MT;
    const int m0 = mtile * 128;
    const int n0 = ntile * 128;

    const int wave = tid >> 6;
    const int lane = tid & 63;
    const int wm = wave >> 1;                 // 0..1  (64-row half)
    const int wn = wave & 1;                  // 0..1  (64-col half)

    f32x4 acc[4][4];
#pragma unroll
    for (int i = 0; i < 4; ++i)
#pragma unroll
        for (int j = 0; j < 4; ++j) acc[i][j] = (f32x4){0.f, 0.f, 0.f, 0.f};

    // staging geometry: chunk = 1KB (64 lanes x 16B) = 8 rows of 128B
    const int srow = (wave << 5) + (lane >> 3);        // + i*8
    const int scol = (lane & 7) << 3;                  // element col (8 bf16)

    for (int k0 = 0; k0 < K; k0 += 64) {
#pragma unroll
        for (int i = 0; i < 4; ++i) {
            const int row = srow + i * 8;
            int gm = m0 + row; gm = (gm < M) ? gm : (M - 1);   // tail clamp
            const unsigned short* gp = A + (size_t)gm * K + k0 + scol;
            __builtin_amdgcn_global_load_lds(
                (const __attribute__((address_space(1))) void*)gp,
                (__attribute__((address_space(3))) void*)&As[(wave * 2048) + i * 512],
                16, 0, 0);
        }
#pragma unroll
        for (int i = 0; i < 4; ++i) {
            const int row = srow + i * 8;
            const unsigned short* gp = Wt + (size_t)(n0 + row) * K + k0 + scol;
            __builtin_amdgcn_global_load_lds(
                (const __attribute__((address_space(1))) void*)gp,
                (__attribute__((address_space(3))) void*)&Bs[(wave * 2048) + i * 512],
                16, 0, 0);
        }
        asm volatile("s_waitcnt vmcnt(0)" ::: "memory");
        __syncthreads();

        const int lr = lane & 15;
        const int lk = (lane >> 4) << 3;
#pragma unroll
        for (int kk = 0; kk < 64; kk += 32) {
            bf16x8 af[4], bg[4];
#pragma unroll
            for (int f = 0; f < 4; ++f) {
                af[f] = *(const bf16x8*)&As[(wm * 64 + f * 16 + lr) * 64 + kk + lk];
                bg[f] = *(const bf16x8*)&Bs[(wn * 64 + f * 16 + lr) * 64 + kk + lk];
            }
#pragma unroll
            for (int mf = 0; mf < 4; ++mf)
#pragma unroll
                for (int nf = 0; nf < 4; ++nf)
                    acc[mf][nf] = __builtin_amdgcn_mfma_f32_16x16x32_bf16(
                        af[mf], bg[nf], acc[mf][nf], 0, 0, 0);
        }
        __syncthreads();
    }

    // epilogue: C/D layout col=lane&15, row=(lane>>4)*4+reg  [m89/m91]
    const int lr = lane & 15;
    const int lg = lane >> 4;
#pragma unroll
    for (int mf = 0; mf < 4; ++mf) {
#pragma unroll
        for (int r = 0; r < 4; ++r) {
            const int row = m0 + wm * 64 + mf * 16 + lg * 4 + r;
            if (row >= M) continue;
#pragma unroll
            for (int nf = 0; nf < 4; ++nf) {
                const int col = n0 + wn * 64 + nf * 16 + lr;
                float v = acc[mf][nf][r] + Bias[col];
                if (RELU) v = fmaxf(v, 0.f);
                if (HAS_RES) v += bf2f(Res[(size_t)row * N + col]);
                if (SF32) Cf[(size_t)row * N + col] = v;
                else      Cb[(size_t)row * N + col] = f2bf(v);
            }
        }
    }
}

// ----------------- fused prep: 9x weight transpose + x cvt + cnt zero -------
struct PrepArgs {
    const float* W[9];
    unsigned short* Wt[9];
    int wstart[10];
    int Kd[9], Nd[9];
    const float* x;
    unsigned short* xbf;
    int* cnt;
    int wtTotal, cvtBlocks, nCvt4, nCnt;
};

__global__ __launch_bounds__(256)
void prep_kernel(PrepArgs a)
{
    __shared__ unsigned short t[64][72];
    const int b = blockIdx.x;
    const int tid = threadIdx.x;
    if (b < a.wtTotal) {
        int job = 0;
        while (b >= a.wstart[job + 1]) ++job;
        const int lb = b - a.wstart[job];
        const int K = a.Kd[job], N = a.Nd[job];
        const int kt = K >> 6;
        const int kb = (lb % kt) * 64, nb = (lb / kt) * 64;
        const float* W = a.W[job];
        unsigned short* Wt = a.Wt[job];
        const int kl = tid >> 4, n4 = (tid & 15) << 2;
#pragma unroll
        for (int it = 0; it < 4; ++it) {
            const int k = kl + it * 16;
            const float4 v = *(const float4*)&W[(size_t)(kb + k) * N + nb + n4];
            t[n4 + 0][k] = f2bf(v.x); t[n4 + 1][k] = f2bf(v.y);
            t[n4 + 2][k] = f2bf(v.z); t[n4 + 3][k] = f2bf(v.w);
        }
        __syncthreads();
        const int n = tid >> 2, kc = (tid & 3) << 4;
        *(uint4*)&Wt[(size_t)(nb + n) * K + kb + kc]     = *(const uint4*)&t[n][kc];
        *(uint4*)&Wt[(size_t)(nb + n) * K + kb + kc + 8] = *(const uint4*)&t[n][kc + 8];
    } else if (b < a.wtTotal + a.cvtBlocks) {
        const int i = (b - a.wtTotal) * 256 + tid;
        if (i < a.nCvt4) {
            const float4 v = ((const float4*)a.x)[i];
            ushort4 o;
            o.x = f2bf(v.x); o.y = f2bf(v.y); o.z = f2bf(v.z); o.w = f2bf(v.w);
            ((ushort4*)a.xbf)[i] = o;
        }
    } else {
        const int i = (b - a.wtTotal - a.cvtBlocks) * 256 + tid;
        if (i < a.nCnt) a.cnt[i] = 0;
    }
}

// ------------------------- CSR build (counting sort) ------------------------
__global__ __launch_bounds__(256)
void hist_kernel(const int* __restrict__ ei, int* __restrict__ cnt, int E)
{
    const int e = blockIdx.x * 256 + threadIdx.x;
    if (e < E) atomicAdd(&cnt[ei[E + e]], 1);
}

__global__ __launch_bounds__(256)
void scan_reduce(const int* __restrict__ cnt, int* __restrict__ bsum, int N)
{
    __shared__ int s[256];
    const int i = blockIdx.x * 256 + threadIdx.x;
    s[threadIdx.x] = (i < N) ? cnt[i] : 0;
    __syncthreads();
#pragma unroll
    for (int off = 128; off > 0; off >>= 1) {
        if (threadIdx.x < off) s[threadIdx.x] += s[threadIdx.x + off];
        __syncthreads();
    }
    if (threadIdx.x == 0) bsum[blockIdx.x] = s[0];
}

__global__ __launch_bounds__(512)
void scan_blocksums(int* __restrict__ bsum, int NB)
{
    __shared__ int a[512], b[512];
    const int t = threadIdx.x;
    const int v = (t < NB) ? bsum[t] : 0;
    a[t] = v;
    __syncthreads();
    int* s = a; int* d = b;
    for (int off = 1; off < 512; off <<= 1) {
        int x = s[t];
        if (t >= off) x += s[t - off];
        d[t] = x;
        __syncthreads();
        int* tmp = s; s = d; d = tmp;
    }
    if (t < NB) bsum[t] = s[t] - v;
}

__global__ __launch_bounds__(256)
void scan_final(const int* __restrict__ cnt, const int* __restrict__ bpre,
                int* __restrict__ off, int* __restrict__ cur, int N)
{
    __shared__ int a[256], b[256];
    const int i = blockIdx.x * 256 + threadIdx.x;
    const int t = threadIdx.x;
    const int v = (i < N) ? cnt[i] : 0;
    a[t] = v;
    __syncthreads();
    int* s = a; int* d = b;
    for (int o = 1; o < 256; o <<= 1) {
        int x = s[t];
        if (t >= o) x += s[t - o];
        d[t] = x;
        __syncthreads();
        int* tmp = s; s = d; d = tmp;
    }
    const int excl = s[t] - v + bpre[blockIdx.x];
    if (i < N) {
        off[i] = excl;
        cur[i] = excl;
        if (i == N - 1) off[N] = excl + v;
    }
}

// 2 waves per node (128 ch each): hpg[i] = h[i] + sum h[src]
__global__ __launch_bounds__(256)
void agg_kernel(const unsigned short* __restrict__ hbf, const int* __restrict__ off,
                const int* __restrict__ ssrc, unsigned short* __restrict__ hpg, int Nn)
{
    const int gw   = (int)((blockIdx.x * 256 + threadIdx.x) >> 6);
    const int lane = threadIdx.x & 63;
    const int node = gw >> 1;
    if (node >= Nn) return;
    const int ci = (gw & 1) * 64 + lane;            // uint column 0..127
    const int e0 = off[node], e1 = off[node + 1];
    const unsigned int* base = (const unsigned int*)hbf;

    unsigned int u = base[(size_t)node * 128 + ci];
    float a0 = bf2f(u & 0xffffu), a1 = bf2f(u >> 16);

    int e = e0;
    for (; e + 3 < e1; e += 4) {
        const unsigned int v0 = base[(size_t)ssrc[e]     * 128 + ci];
        const unsigned int v1 = base[(size_t)ssrc[e + 1] * 128 + ci];
        const unsigned int v2 = base[(size_t)ssrc[e + 2] * 128 + ci];
        const unsigned int v3 = base[(size_t)ssrc[e + 3] * 128 + ci];
        a0 += bf2f(v0 & 0xffffu) + bf2f(v1 & 0xffffu) + bf2f(v2 & 0xffffu) + bf2f(v3 & 0xffffu);
        a1 += bf2f(v0 >> 16)     + bf2f(v1 >> 16)     + bf2f(v2 >> 16)     + bf2f(v3 >> 16);
    }
    for (; e < e1; ++e) {
        const unsigned int v0 = base[(size_t)ssrc[e] * 128 + ci];
        a0 += bf2f(v0 & 0xffffu); a1 += bf2f(v0 >> 16);
    }
    ((unsigned int*)hpg)[(size_t)node * 128 + ci] =
        (unsigned)f2bf(a0) | ((unsigned)f2bf(a1) << 16);
}

// ---------------------------------------------------------------------------

extern "C" void kernel_launch(void* const* d_in, const int* in_sizes, int n_in,
                              void* d_out, int out_size, void* d_ws, size_t ws_size,
                              hipStream_t stream)
{
    const float* x  = (const float*)d_in[0];
    const int*   ei = (const int*)d_in[1];
    const float* W[9]  = {(const float*)d_in[3],  (const float*)d_in[5],  (const float*)d_in[7],
                          (const float*)d_in[9],  (const float*)d_in[11], (const float*)d_in[13],
                          (const float*)d_in[15], (const float*)d_in[17], (const float*)d_in[19]};
    const float* B[9]  = {(const float*)d_in[4],  (const float*)d_in[6],  (const float*)d_in[8],
                          (const float*)d_in[10], (const float*)d_in[12], (const float*)d_in[14],
                          (const float*)d_in[16], (const float*)d_in[18], (const float*)d_in[20]};
    const int    Kd[9] = {128, 512, 512, 256, 512, 512, 256, 512, 512};
    const int    Nd[9] = {512, 512, 256, 512, 512, 256, 512, 512, 128};
    float* out = (float*)d_out;

    const int M = 100000;
    const int E = 1600000;
    const size_t HN = (size_t)M * 256;
    const int ORDER_BLOCKS = 1536;

    char* p = (char*)d_ws;
    auto carve = [&](size_t bytes) -> char* {
        char* r = p;
        p += (bytes + 255) & ~(size_t)255;
        return r;
    };
    unsigned short* hbf   = (unsigned short*)carve(HN * 2);
    unsigned short* hpgbf = (unsigned short*)carve(HN * 2);
    unsigned short* xbf   = (unsigned short*)carve((size_t)M * 128 * 2);
    unsigned short* Wt[9];
    for (int i = 0; i < 9; ++i) Wt[i] = (unsigned short*)carve((size_t)Kd[i] * Nd[i] * 2);
    int* cnt  = (int*)carve(M * 4);
    int* off  = (int*)carve((M + 4) * 4);
    int* cur  = (int*)carve(M * 4);
    int* bsum = (int*)carve(512 * 4);
    int* ssrc = (int*)carve((size_t)E * 4);

    // balanced M-chunking for t1/t2 (512-wide bf16 intermediates)
    const size_t fixed = (size_t)(p - (char*)d_ws);
    size_t remain = (ws_size > fixed) ? ws_size - fixed : 0;
    size_t cap = remain / (2 * 512 * 2);           // rows that fit (t1+t2)
    if (cap < 4096) cap = 4096;                    // last-resort floor
    const int nch = (cap >= (size_t)M) ? 1 : (int)((M + cap - 1) / cap);
    const int CH = (M + nch - 1) / nch;
    unsigned short* t1 = (unsigned short*)carve((size_t)CH * 512 * 2);
    unsigned short* t2 = (unsigned short*)carve((size_t)CH * 512 * 2);

    const dim3 blk(256);
    const int NB = (M + 255) / 256;

    // ---- fused prep: weight transposes + x convert + cnt zero ----
    PrepArgs pa;
    pa.wstart[0] = 0;
    for (int i = 0; i < 9; ++i) {
        pa.W[i] = W[i]; pa.Wt[i] = Wt[i]; pa.Kd[i] = Kd[i]; pa.Nd[i] = Nd[i];
        pa.wstart[i + 1] = pa.wstart[i] + (Kd[i] / 64) * (Nd[i] / 64);
    }
    pa.x = x; pa.xbf = xbf; pa.cnt = cnt;
    pa.wtTotal = pa.wstart[9];
    pa.nCvt4 = M * 128 / 4;
    pa.cvtBlocks = (pa.nCvt4 + 255) / 256;
    pa.nCnt = M;
    prep_kernel<<<pa.wtTotal + pa.cvtBlocks + NB, blk, 0, stream>>>(pa);

    // ---- CSR histogram + scan (order is fused into enc1 below) ----
    hist_kernel<<<(E + 255) / 256, blk, 0, stream>>>(ei, cnt, E);
    scan_reduce<<<NB, blk, 0, stream>>>(cnt, bsum, M);
    scan_blocksums<<<1, 512, 0, stream>>>(bsum, NB);
    scan_final<<<NB, blk, 0, stream>>>(cnt, bsum, off, cur, M);

    auto mt = [](int m) { return (m + 127) / 128; };

    // ---- encoder (order backfilled into first enc1 launch) ----
    for (int m0 = 0; m0 < M; m0 += CH) {
        const int cm = (M - m0 < CH) ? (M - m0) : CH;
        const int MT = mt(cm);
        if (m0 == 0) {
            gemm128<true, false, false, true><<<MT * 4 + ORDER_BLOCKS, blk, 0, stream>>>(
                xbf, Wt[0], B[0], nullptr, nullptr, t1, cm, 128, 512, MT,
                MT * 4, ei, cur, ssrc, E);
        } else {
            gemm128<true, false, false, false><<<MT * 4, blk, 0, stream>>>(
                xbf + (size_t)m0 * 128, Wt[0], B[0], nullptr, nullptr, t1,
                cm, 128, 512, MT, 0, nullptr, nullptr, nullptr, 0);
        }
        gemm128<true, false, false, false><<<MT * 4, blk, 0, stream>>>(
            t1, Wt[1], B[1], nullptr, nullptr, t2, cm, 512, 512, MT,
            0, nullptr, nullptr, nullptr, 0);
        gemm128<true, false, false, false><<<MT * 2, blk, 0, stream>>>(
            t2, Wt[2], B[2], nullptr, nullptr, hbf + (size_t)m0 * 256, cm, 512, 256, MT,
            0, nullptr, nullptr, nullptr, 0);
    }

    // ---- aggregation: hpg = h + sum_{src->i} h[src] ----
    agg_kernel<<<(int)(((size_t)2 * M * 64 + 255) / 256), blk, 0, stream>>>(
        hbf, off, ssrc, hpgbf, M);

    // ---- conv MLP (+ residual h) ----
    for (int m0 = 0; m0 < M; m0 += CH) {
        const int cm = (M - m0 < CH) ? (M - m0) : CH;
        const int MT = mt(cm);
        gemm128<true, false, false, false><<<MT * 4, blk, 0, stream>>>(
            hpgbf + (size_t)m0 * 256, Wt[3], B[3], nullptr, nullptr, t1, cm, 256, 512, MT,
            0, nullptr, nullptr, nullptr, 0);
        gemm128<true, false, false, false><<<MT * 4, blk, 0, stream>>>(
            t1, Wt[4], B[4], nullptr, nullptr, t2, cm, 512, 512, MT,
            0, nullptr, nullptr, nullptr, 0);
        gemm128<true, true, false, false><<<MT * 2, blk, 0, stream>>>(
            t2, Wt[5], B[5], hbf + (size_t)m0 * 256, nullptr, hpgbf + (size_t)m0 * 256,
            cm, 512, 256, MT, 0, nullptr, nullptr, nullptr, 0);
    }

    // ---- decoder: hpg ->(relu) t1 ->(relu) t2 -> out (f32, no act) ----
    for (int m0 = 0; m0 < M; m0 += CH) {
        const int cm = (M - m0 < CH) ? (M - m0) : CH;
        const int MT = mt(cm);
        gemm128<true, false, false, false><<<MT * 4, blk, 0, stream>>>(
            hpgbf + (size_t)m0 * 256, Wt[6], B[6], nullptr, nullptr, t1, cm, 256, 512, MT,
            0, nullptr, nullptr, nullptr, 0);
        gemm128<true, false, false, false><<<MT * 4, blk, 0, stream>>>(
            t1, Wt[7], B[7], nullptr, nullptr, t2, cm, 512, 512, MT,
            0, nullptr, nullptr, nullptr, 0);
        gemm128<false, false, true, false><<<MT, blk, 0, stream>>>(
            t2, Wt[8], B[8], nullptr, out + (size_t)m0 * 128, nullptr, cm, 512, 128, MT,
            0, nullptr, nullptr, nullptr, 0);
    }
}

// Round 7
// 937.326 us; speedup vs baseline: 1.5462x; 1.1213x over previous
//
#include <hip/hip_runtime.h>
#include <cstdint>
#include <cstddef>

// ---------------------------------------------------------------------------
// GIN forward, bf16-MFMA (m97 128^2 GEMM structure).
// Round 7: order fused FIRST into enc2 (real overlap), hist fused into prep,
// 8-deep ILP gather in agg, launch_bounds(256,4).
// ---------------------------------------------------------------------------

typedef __attribute__((ext_vector_type(8))) __bf16 bf16x8;
typedef __attribute__((ext_vector_type(4))) float f32x4;

__device__ __forceinline__ unsigned short f2bf(float f) {
    unsigned int u = __float_as_uint(f);
    u += 0x7FFF + ((u >> 16) & 1);          // RNE
    return (unsigned short)(u >> 16);
}
__device__ __forceinline__ float bf2f(unsigned int s) {
    return __uint_as_float(s << 16);
}

// ---------------------------- bf16 MFMA GEMM --------------------------------
// C[M,N] = epilogue(A[M,K](bf16) @ W[K,N]) with W transposed: Wt[N,K].
// 128x128 tile, 4 waves, BK=64, global_load_lds 16B staging (m97 structure).
// ORDER: blocks [0, orderBlocks) run the CSR bucket-scatter; gemm blocks after.
template<bool RELU, bool HAS_RES, bool SF32, bool ORDER>
__global__ __launch_bounds__(256, 4)
void gemm128(const unsigned short* __restrict__ A,
             const unsigned short* __restrict__ Wt,
             const float* __restrict__ Bias,
             const unsigned short* __restrict__ Res,
             float* __restrict__ Cf, unsigned short* __restrict__ Cb,
             int M, int K, int N, int MT, int orderBlocks,
             const int* __restrict__ ei, int* __restrict__ cur,
             int* __restrict__ ssrc, int E)
{
    __shared__ unsigned short As[128 * 64];   // [row 0..127][k 0..63]
    __shared__ unsigned short Bs[128 * 64];   // [n   0..127][k 0..63]

    const int tid  = threadIdx.x;

    if (ORDER && (int)blockIdx.x < orderBlocks) {
        // CSR bucket scatter: pos = cur[dst]++; ssrc[pos] = src.
        const int nth = orderBlocks * 256;
        for (int e = (int)blockIdx.x * 256 + tid; e < E; e += nth) {
            const int s = ei[e];
            const int d = ei[E + e];
            const int pos = atomicAdd(&cur[d], 1);
            ssrc[pos] = s;
        }
        return;
    }

    const int bid = ORDER ? ((int)blockIdx.x - orderBlocks) : (int)blockIdx.x;
    const int mtile = bid % MT;
    const int ntile = bid / MT;
    const int m0 = mtile * 128;
    const int n0 = ntile * 128;

    const int wave = tid >> 6;
    const int lane = tid & 63;
    const int wm = wave >> 1;                 // 0..1  (64-row half)
    const int wn = wave & 1;                  // 0..1  (64-col half)

    f32x4 acc[4][4];
#pragma unroll
    for (int i = 0; i < 4; ++i)
#pragma unroll
        for (int j = 0; j < 4; ++j) acc[i][j] = (f32x4){0.f, 0.f, 0.f, 0.f};

    // staging geometry: chunk = 1KB (64 lanes x 16B) = 8 rows of 128B
    const int srow = (wave << 5) + (lane >> 3);        // + i*8
    const int scol = (lane & 7) << 3;                  // element col (8 bf16)

    for (int k0 = 0; k0 < K; k0 += 64) {
#pragma unroll
        for (int i = 0; i < 4; ++i) {
            const int row = srow + i * 8;
            int gm = m0 + row; gm = (gm < M) ? gm : (M - 1);   // tail clamp
            const unsigned short* gp = A + (size_t)gm * K + k0 + scol;
            __builtin_amdgcn_global_load_lds(
                (const __attribute__((address_space(1))) void*)gp,
                (__attribute__((address_space(3))) void*)&As[(wave * 2048) + i * 512],
                16, 0, 0);
        }
#pragma unroll
        for (int i = 0; i < 4; ++i) {
            const int row = srow + i * 8;
            const unsigned short* gp = Wt + (size_t)(n0 + row) * K + k0 + scol;
            __builtin_amdgcn_global_load_lds(
                (const __attribute__((address_space(1))) void*)gp,
                (__attribute__((address_space(3))) void*)&Bs[(wave * 2048) + i * 512],
                16, 0, 0);
        }
        asm volatile("s_waitcnt vmcnt(0)" ::: "memory");
        __syncthreads();

        const int lr = lane & 15;
        const int lk = (lane >> 4) << 3;
#pragma unroll
        for (int kk = 0; kk < 64; kk += 32) {
            bf16x8 af[4], bg[4];
#pragma unroll
            for (int f = 0; f < 4; ++f) {
                af[f] = *(const bf16x8*)&As[(wm * 64 + f * 16 + lr) * 64 + kk + lk];
                bg[f] = *(const bf16x8*)&Bs[(wn * 64 + f * 16 + lr) * 64 + kk + lk];
            }
#pragma unroll
            for (int mf = 0; mf < 4; ++mf)
#pragma unroll
                for (int nf = 0; nf < 4; ++nf)
                    acc[mf][nf] = __builtin_amdgcn_mfma_f32_16x16x32_bf16(
                        af[mf], bg[nf], acc[mf][nf], 0, 0, 0);
        }
        __syncthreads();
    }

    // epilogue: C/D layout col=lane&15, row=(lane>>4)*4+reg  [m89/m91]
    const int lr = lane & 15;
    const int lg = lane >> 4;
#pragma unroll
    for (int mf = 0; mf < 4; ++mf) {
#pragma unroll
        for (int r = 0; r < 4; ++r) {
            const int row = m0 + wm * 64 + mf * 16 + lg * 4 + r;
            if (row >= M) continue;
#pragma unroll
            for (int nf = 0; nf < 4; ++nf) {
                const int col = n0 + wn * 64 + nf * 16 + lr;
                float v = acc[mf][nf][r] + Bias[col];
                if (RELU) v = fmaxf(v, 0.f);
                if (HAS_RES) v += bf2f(Res[(size_t)row * N + col]);
                if (SF32) Cf[(size_t)row * N + col] = v;
                else      Cb[(size_t)row * N + col] = f2bf(v);
            }
        }
    }
}

// --------- fused prep: hist (first) + 9x weight transpose + x cvt -----------
struct PrepArgs {
    const float* W[9];
    unsigned short* Wt[9];
    int wstart[10];
    int Kd[9], Nd[9];
    const float* x;
    unsigned short* xbf;
    const int* ei;
    int* cnt;
    int histBlocks, wtTotal, nCvt4, E;
};

__global__ __launch_bounds__(256)
void prep_kernel(PrepArgs a)
{
    __shared__ unsigned short t[64][72];
    int b = blockIdx.x;
    const int tid = threadIdx.x;
    if (b < a.histBlocks) {
        // histogram of dst (cnt pre-zeroed in a prior launch)
        const int nth = a.histBlocks * 256;
        for (int e = b * 256 + tid; e < a.E; e += nth)
            atomicAdd(&a.cnt[a.ei[a.E + e]], 1);
        return;
    }
    b -= a.histBlocks;
    if (b < a.wtTotal) {
        int job = 0;
        while (b >= a.wstart[job + 1]) ++job;
        const int lb = b - a.wstart[job];
        const int K = a.Kd[job], N = a.Nd[job];
        const int kt = K >> 6;
        const int kb = (lb % kt) * 64, nb = (lb / kt) * 64;
        const float* W = a.W[job];
        unsigned short* Wt = a.Wt[job];
        const int kl = tid >> 4, n4 = (tid & 15) << 2;
#pragma unroll
        for (int it = 0; it < 4; ++it) {
            const int k = kl + it * 16;
            const float4 v = *(const float4*)&W[(size_t)(kb + k) * N + nb + n4];
            t[n4 + 0][k] = f2bf(v.x); t[n4 + 1][k] = f2bf(v.y);
            t[n4 + 2][k] = f2bf(v.z); t[n4 + 3][k] = f2bf(v.w);
        }
        __syncthreads();
        const int n = tid >> 2, kc = (tid & 3) << 4;
        *(uint4*)&Wt[(size_t)(nb + n) * K + kb + kc]     = *(const uint4*)&t[n][kc];
        *(uint4*)&Wt[(size_t)(nb + n) * K + kb + kc + 8] = *(const uint4*)&t[n][kc + 8];
        return;
    }
    b -= a.wtTotal;
    const int i = b * 256 + tid;
    if (i < a.nCvt4) {
        const float4 v = ((const float4*)a.x)[i];
        ushort4 o;
        o.x = f2bf(v.x); o.y = f2bf(v.y); o.z = f2bf(v.z); o.w = f2bf(v.w);
        ((ushort4*)a.xbf)[i] = o;
    }
}

// ------------------------- CSR scan chain -----------------------------------
__global__ __launch_bounds__(256)
void zero_ints(int* __restrict__ p, int n)
{
    const int i = blockIdx.x * 256 + threadIdx.x;
    if (i < n) p[i] = 0;
}

__global__ __launch_bounds__(256)
void scan_reduce(const int* __restrict__ cnt, int* __restrict__ bsum, int N)
{
    __shared__ int s[256];
    const int i = blockIdx.x * 256 + threadIdx.x;
    s[threadIdx.x] = (i < N) ? cnt[i] : 0;
    __syncthreads();
#pragma unroll
    for (int off = 128; off > 0; off >>= 1) {
        if (threadIdx.x < off) s[threadIdx.x] += s[threadIdx.x + off];
        __syncthreads();
    }
    if (threadIdx.x == 0) bsum[blockIdx.x] = s[0];
}

__global__ __launch_bounds__(512)
void scan_blocksums(int* __restrict__ bsum, int NB)
{
    __shared__ int a[512], b[512];
    const int t = threadIdx.x;
    const int v = (t < NB) ? bsum[t] : 0;
    a[t] = v;
    __syncthreads();
    int* s = a; int* d = b;
    for (int off = 1; off < 512; off <<= 1) {
        int x = s[t];
        if (t >= off) x += s[t - off];
        d[t] = x;
        __syncthreads();
        int* tmp = s; s = d; d = tmp;
    }
    if (t < NB) bsum[t] = s[t] - v;
}

__global__ __launch_bounds__(256)
void scan_final(const int* __restrict__ cnt, const int* __restrict__ bpre,
                int* __restrict__ off, int* __restrict__ cur, int N)
{
    __shared__ int a[256], b[256];
    const int i = blockIdx.x * 256 + threadIdx.x;
    const int t = threadIdx.x;
    const int v = (i < N) ? cnt[i] : 0;
    a[t] = v;
    __syncthreads();
    int* s = a; int* d = b;
    for (int o = 1; o < 256; o <<= 1) {
        int x = s[t];
        if (t >= o) x += s[t - o];
        d[t] = x;
        __syncthreads();
        int* tmp = s; s = d; d = tmp;
    }
    const int excl = s[t] - v + bpre[blockIdx.x];
    if (i < N) {
        off[i] = excl;
        cur[i] = excl;
        if (i == N - 1) off[N] = excl + v;
    }
}

// 2 waves per node (128 uint cols each): hpg[i] = h[i] + sum h[src]
// 8-deep static-unrolled gather for load ILP.
__global__ __launch_bounds__(256)
void agg_kernel(const unsigned short* __restrict__ hbf, const int* __restrict__ off,
                const int* __restrict__ ssrc, unsigned short* __restrict__ hpg, int Nn)
{
    const int gw   = (int)((blockIdx.x * 256 + threadIdx.x) >> 6);
    const int lane = threadIdx.x & 63;
    const int node = gw >> 1;
    if (node >= Nn) return;
    const int ci = (gw & 1) * 64 + lane;            // uint column 0..127
    const int e0 = off[node], e1 = off[node + 1];
    const unsigned int* base = (const unsigned int*)hbf;

    unsigned int u = base[(size_t)node * 128 + ci];
    float a0 = bf2f(u & 0xffffu), a1 = bf2f(u >> 16);

    int e = e0;
    for (; e + 7 < e1; e += 8) {
        int s[8];
#pragma unroll
        for (int j = 0; j < 8; ++j) s[j] = ssrc[e + j];
        unsigned int v[8];
#pragma unroll
        for (int j = 0; j < 8; ++j) v[j] = base[(size_t)s[j] * 128 + ci];
#pragma unroll
        for (int j = 0; j < 8; ++j) {
            a0 += bf2f(v[j] & 0xffffu);
            a1 += bf2f(v[j] >> 16);
        }
    }
    for (; e + 1 < e1; e += 2) {
        const unsigned int v0 = base[(size_t)ssrc[e]     * 128 + ci];
        const unsigned int v1 = base[(size_t)ssrc[e + 1] * 128 + ci];
        a0 += bf2f(v0 & 0xffffu) + bf2f(v1 & 0xffffu);
        a1 += bf2f(v0 >> 16)     + bf2f(v1 >> 16);
    }
    if (e < e1) {
        const unsigned int v0 = base[(size_t)ssrc[e] * 128 + ci];
        a0 += bf2f(v0 & 0xffffu); a1 += bf2f(v0 >> 16);
    }
    ((unsigned int*)hpg)[(size_t)node * 128 + ci] =
        (unsigned)f2bf(a0) | ((unsigned)f2bf(a1) << 16);
}

// ---------------------------------------------------------------------------

extern "C" void kernel_launch(void* const* d_in, const int* in_sizes, int n_in,
                              void* d_out, int out_size, void* d_ws, size_t ws_size,
                              hipStream_t stream)
{
    const float* x  = (const float*)d_in[0];
    const int*   ei = (const int*)d_in[1];
    const float* W[9]  = {(const float*)d_in[3],  (const float*)d_in[5],  (const float*)d_in[7],
                          (const float*)d_in[9],  (const float*)d_in[11], (const float*)d_in[13],
                          (const float*)d_in[15], (const float*)d_in[17], (const float*)d_in[19]};
    const float* B[9]  = {(const float*)d_in[4],  (const float*)d_in[6],  (const float*)d_in[8],
                          (const float*)d_in[10], (const float*)d_in[12], (const float*)d_in[14],
                          (const float*)d_in[16], (const float*)d_in[18], (const float*)d_in[20]};
    const int    Kd[9] = {128, 512, 512, 256, 512, 512, 256, 512, 512};
    const int    Nd[9] = {512, 512, 256, 512, 512, 256, 512, 512, 128};
    float* out = (float*)d_out;

    const int M = 100000;
    const int E = 1600000;
    const size_t HN = (size_t)M * 256;
    const int ORDER_BLOCKS = 768;
    const int HIST_BLOCKS  = 1024;

    char* p = (char*)d_ws;
    auto carve = [&](size_t bytes) -> char* {
        char* r = p;
        p += (bytes + 255) & ~(size_t)255;
        return r;
    };
    unsigned short* hbf   = (unsigned short*)carve(HN * 2);
    unsigned short* hpgbf = (unsigned short*)carve(HN * 2);
    unsigned short* xbf   = (unsigned short*)carve((size_t)M * 128 * 2);
    unsigned short* Wt[9];
    for (int i = 0; i < 9; ++i) Wt[i] = (unsigned short*)carve((size_t)Kd[i] * Nd[i] * 2);
    int* cnt  = (int*)carve(M * 4);
    int* off  = (int*)carve((M + 4) * 4);
    int* cur  = (int*)carve(M * 4);
    int* bsum = (int*)carve(512 * 4);
    int* ssrc = (int*)carve((size_t)E * 4);

    // balanced M-chunking for t1/t2 (512-wide bf16 intermediates)
    const size_t fixed = (size_t)(p - (char*)d_ws);
    size_t remain = (ws_size > fixed) ? ws_size - fixed : 0;
    size_t cap = remain / (2 * 512 * 2);           // rows that fit (t1+t2)
    if (cap < 4096) cap = 4096;                    // last-resort floor
    const int nch = (cap >= (size_t)M) ? 1 : (int)((M + cap - 1) / cap);
    const int CH = (M + nch - 1) / nch;
    unsigned short* t1 = (unsigned short*)carve((size_t)CH * 512 * 2);
    unsigned short* t2 = (unsigned short*)carve((size_t)CH * 512 * 2);

    const dim3 blk(256);
    const int NB = (M + 255) / 256;

    // ---- cnt zero, then fused prep: hist(first) + wt transposes + x cvt ----
    zero_ints<<<NB, blk, 0, stream>>>(cnt, M);

    PrepArgs pa;
    pa.wstart[0] = 0;
    for (int i = 0; i < 9; ++i) {
        pa.W[i] = W[i]; pa.Wt[i] = Wt[i]; pa.Kd[i] = Kd[i]; pa.Nd[i] = Nd[i];
        pa.wstart[i + 1] = pa.wstart[i] + (Kd[i] / 64) * (Nd[i] / 64);
    }
    pa.x = x; pa.xbf = xbf; pa.ei = ei; pa.cnt = cnt;
    pa.histBlocks = HIST_BLOCKS;
    pa.wtTotal = pa.wstart[9];
    pa.nCvt4 = M * 128 / 4;
    pa.E = E;
    const int cvtBlocks = (pa.nCvt4 + 255) / 256;
    prep_kernel<<<HIST_BLOCKS + pa.wtTotal + cvtBlocks, blk, 0, stream>>>(pa);

    // ---- scan chain ----
    scan_reduce<<<NB, blk, 0, stream>>>(cnt, bsum, M);
    scan_blocksums<<<1, 512, 0, stream>>>(bsum, NB);
    scan_final<<<NB, blk, 0, stream>>>(cnt, bsum, off, cur, M);

    auto mt = [](int m) { return (m + 127) / 128; };

    // ---- encoder; order fused FIRST into the first enc2 launch ----
    for (int m0 = 0; m0 < M; m0 += CH) {
        const int cm = (M - m0 < CH) ? (M - m0) : CH;
        const int MT = mt(cm);
        gemm128<true, false, false, false><<<MT * 4, blk, 0, stream>>>(
            xbf + (size_t)m0 * 128, Wt[0], B[0], nullptr, nullptr, t1,
            cm, 128, 512, MT, 0, nullptr, nullptr, nullptr, 0);
        if (m0 == 0) {
            gemm128<true, false, false, true><<<ORDER_BLOCKS + MT * 4, blk, 0, stream>>>(
                t1, Wt[1], B[1], nullptr, nullptr, t2, cm, 512, 512, MT,
                ORDER_BLOCKS, ei, cur, ssrc, E);
        } else {
            gemm128<true, false, false, false><<<MT * 4, blk, 0, stream>>>(
                t1, Wt[1], B[1], nullptr, nullptr, t2, cm, 512, 512, MT,
                0, nullptr, nullptr, nullptr, 0);
        }
        gemm128<true, false, false, false><<<MT * 2, blk, 0, stream>>>(
            t2, Wt[2], B[2], nullptr, nullptr, hbf + (size_t)m0 * 256, cm, 512, 256, MT,
            0, nullptr, nullptr, nullptr, 0);
    }

    // ---- aggregation: hpg = h + sum_{src->i} h[src] ----
    agg_kernel<<<(int)(((size_t)2 * M * 64 + 255) / 256), blk, 0, stream>>>(
        hbf, off, ssrc, hpgbf, M);

    // ---- conv MLP (+ residual h) ----
    for (int m0 = 0; m0 < M; m0 += CH) {
        const int cm = (M - m0 < CH) ? (M - m0) : CH;
        const int MT = mt(cm);
        gemm128<true, false, false, false><<<MT * 4, blk, 0, stream>>>(
            hpgbf + (size_t)m0 * 256, Wt[3], B[3], nullptr, nullptr, t1, cm, 256, 512, MT,
            0, nullptr, nullptr, nullptr, 0);
        gemm128<true, false, false, false><<<MT * 4, blk, 0, stream>>>(
            t1, Wt[4], B[4], nullptr, nullptr, t2, cm, 512, 512, MT,
            0, nullptr, nullptr, nullptr, 0);
        gemm128<true, true, false, false><<<MT * 2, blk, 0, stream>>>(
            t2, Wt[5], B[5], hbf + (size_t)m0 * 256, nullptr, hpgbf + (size_t)m0 * 256,
            cm, 512, 256, MT, 0, nullptr, nullptr, nullptr, 0);
    }

    // ---- decoder: hpg ->(relu) t1 ->(relu) t2 -> out (f32, no act) ----
    for (int m0 = 0; m0 < M; m0 += CH) {
        const int cm = (M - m0 < CH) ? (M - m0) : CH;
        const int MT = mt(cm);
        gemm128<true, false, false, false><<<MT * 4, blk, 0, stream>>>(
            hpgbf + (size_t)m0 * 256, Wt[6], B[6], nullptr, nullptr, t1, cm, 256, 512, MT,
            0, nullptr, nullptr, nullptr, 0);
        gemm128<true, false, false, false><<<MT * 4, blk, 0, stream>>>(
            t1, Wt[7], B[7], nullptr, nullptr, t2, cm, 512, 512, MT,
            0, nullptr, nullptr, nullptr, 0);
        gemm128<false, false, true, false><<<MT, blk, 0, stream>>>(
            t2, Wt[8], B[8], nullptr, out + (size_t)m0 * 128, nullptr, cm, 512, 128, MT,
            0, nullptr, nullptr, nullptr, 0);
    }
}